// Round 10
// baseline (2046142.188 us; speedup 1.0000x reference)
//
#include <hip/hip_runtime.h>
#include <cstdint>

typedef __attribute__((ext_vector_type(8))) short short8;
typedef __attribute__((ext_vector_type(4))) float f32x4;
typedef __attribute__((ext_vector_type(4))) unsigned u32x4;

#define R_DIM 1024
#define KE    1056      // 1024 state + 8 x + 24 zero pad
#define T_LEN 65536
#define CCH   2048      // chunks
#define LCH   32        // real steps per chunk
#define WARM  12        // warmup steps (validated R9: absmax 0.0307)
#define STEPS (WARM + LCH)   // 44
#define NGRP  32        // groups, 64 cols each
#define WGC   64        // cols per WG
#define RWG   8         // row-WGs per group (128 rows each)
#define LDSB  131072    // 2 halves x 32 cols x 2048B

static __device__ __forceinline__ unsigned short f2bf(float f){
  unsigned u = __builtin_bit_cast(unsigned, f);
  u += 0x7fffu + ((u >> 16) & 1u);
  return (unsigned short)(u >> 16);
}
static __device__ __forceinline__ float fast_tanh(float x){
  float e = __expf(2.0f * x);          // inf/0 saturate correctly to +/-1
  return 1.0f - 2.0f / (e + 1.0f);
}

// ---- prep: W_ext = [W_res | W_in | 0] in bf16, row-major [1024][1056] ----
__global__ void k_build_wext(const float* __restrict__ Wres,
                             const float* __restrict__ Win,
                             short* __restrict__ Wext){
  int idx = blockIdx.x * 256 + threadIdx.x;       // 1024*1056 = 4224*256
  int r = idx / KE, k = idx % KE;
  float v = 0.0f;
  if (k < 1024)      v = Wres[(size_t)r * 1024 + k];
  else if (k < 1032) v = Win[r * 8 + (k - 1024)];
  Wext[idx] = (short)f2bf(v);
}

// ---- prep: zero state region [0,1024) of each chunk's initial-read row ----
__global__ void k_zero_init(short* __restrict__ base, size_t rowstride){
  int idx = blockIdx.x * 256 + threadIdx.x;   // 2048 rows x 512 dwords
  int c = idx >> 9, d = idx & 511;
  ((unsigned*)(base + (size_t)c * rowstride))[d] = 0u;
}

// ---- prep: x-slot of each chunk's initial row, zero flag+xcc area ----
__global__ void k_init_x(const float* __restrict__ in, short* __restrict__ x0,
                         size_t rowstride, unsigned* __restrict__ cnt){
  int c = blockIdx.x * 256 + threadIdx.x;
  if (c < 1024) cnt[c] = 0u;                  // flags (0..511) + xcc slots (512..1023)
  if (c < CCH){
    int t0 = c * LCH - WARM;
    uint4 xv = {0,0,0,0};
    if (t0 >= 0){
      const float4 A4 = *(const float4*)(in + (size_t)t0 * 8);
      const float4 B4 = *(const float4*)(in + (size_t)t0 * 8 + 4);
      xv.x = f2bf(A4.x) | ((unsigned)f2bf(A4.y) << 16);
      xv.y = f2bf(A4.z) | ((unsigned)f2bf(A4.w) << 16);
      xv.z = f2bf(B4.x) | ((unsigned)f2bf(B4.y) << 16);
      xv.w = f2bf(B4.z) | ((unsigned)f2bf(B4.w) << 16);
    }
    *(uint4*)(x0 + (size_t)c * rowstride) = xv;
  }
}

// ---- output rows 1024..1031 = inputs^T (exact fp32 copy) ----
__global__ void k_xrows(const float* __restrict__ in, float* __restrict__ out){
  int t = blockIdx.x * 256 + threadIdx.x;
  const float4 a = *(const float4*)(in + (size_t)t * 8);
  const float4 b = *(const float4*)(in + (size_t)t * 8 + 4);
  out[(size_t)(R_DIM + 0) * T_LEN + t] = a.x;
  out[(size_t)(R_DIM + 1) * T_LEN + t] = a.y;
  out[(size_t)(R_DIM + 2) * T_LEN + t] = a.z;
  out[(size_t)(R_DIM + 3) * T_LEN + t] = a.w;
  out[(size_t)(R_DIM + 4) * T_LEN + t] = b.x;
  out[(size_t)(R_DIM + 5) * T_LEN + t] = b.y;
  out[(size_t)(R_DIM + 6) * T_LEN + t] = b.z;
  out[(size_t)(R_DIM + 7) * T_LEN + t] = b.w;
}

// ---- hist[t][r] (bf16) -> out[r][t] (f32), tiled transpose ----
__global__ void k_transpose(const short* __restrict__ hist, float* __restrict__ out){
  __shared__ float tile[64][65];
  const int t0 = blockIdx.x * 64;
  const int r0 = blockIdx.y * 64;
  for (int it = 0; it < 2; ++it){
    int id = it * 256 + threadIdx.x;     // 512 chunks of 8 bf16
    int tr = id >> 3;
    int c8 = (id & 7) * 8;
    short8 v = *(const short8*)(hist + (size_t)(t0 + tr) * KE + r0 + c8);
    #pragma unroll
    for (int j = 0; j < 8; ++j){
      unsigned u = ((unsigned)(unsigned short)v[j]) << 16;
      tile[tr][c8 + j] = __builtin_bit_cast(float, u);
    }
  }
  __syncthreads();
  #pragma unroll
  for (int p = 0; p < 16; ++p){
    int rr = (threadIdx.x >> 6) + p * 4;
    int tc = threadIdx.x & 63;
    out[(size_t)(r0 + rr) * T_LEN + t0 + tc] = tile[tc][rr];
  }
}

// 8 staging loads + wait, cache-policy parameterized
#define STAGE8(sfx) \
  asm volatile( \
    "global_load_dwordx4 %0, %8, off " sfx "\n\t" \
    "global_load_dwordx4 %1, %8, off offset:256 " sfx "\n\t" \
    "global_load_dwordx4 %2, %8, off offset:512 " sfx "\n\t" \
    "global_load_dwordx4 %3, %8, off offset:768 " sfx "\n\t" \
    "global_load_dwordx4 %4, %8, off offset:1024 " sfx "\n\t" \
    "global_load_dwordx4 %5, %8, off offset:1280 " sfx "\n\t" \
    "global_load_dwordx4 %6, %8, off offset:1536 " sfx "\n\t" \
    "global_load_dwordx4 %7, %8, off offset:1792 " sfx "\n\t" \
    "s_waitcnt vmcnt(0)" \
    : "=&v"(r0),"=&v"(r1),"=&v"(r2),"=&v"(r3), \
      "=&v"(r4),"=&v"(r5),"=&v"(r6),"=&v"(r7) \
    : "v"(sp) : "memory")

// 4 tail dwordx2 loads, no wait (completion covered by staging vmcnt(0),
// consumed only after barrier B)
#define TAIL4(sfx) \
  asm volatile( \
    "global_load_dwordx2 %0, %4, off " sfx "\n\t" \
    "global_load_dwordx2 %1, %4, off offset:8 " sfx "\n\t" \
    "global_load_dwordx2 %2, %5, off " sfx "\n\t" \
    "global_load_dwordx2 %3, %5, off offset:8 " sfx \
    : "=&v"(t00),"=&v"(t01),"=&v"(t10),"=&v"(t11) \
    : "v"(tp0), "v"(tp1) : "memory")

#define POLL1(sfx) \
  asm volatile("global_load_dword %0, %1, off " sfx "\n\t" \
               "s_waitcnt vmcnt(0)" : "=v"(pv) : "v"(fp) : "memory")

// ---- main: 256 WGs x 512 thr (1 WG/CU); WG = 128 rows x 64 cols, 2 halves.
// FAST path (runtime-verified same-XCD group): ALL cross-WG stores AND loads
// use sc0 (L1-bypass, meet in the shared L2; R9 lesson: plain stores sit in
// write-back L1 ~20ms — sc0 on stores is REQUIRED). SLOW fallback: sc0 sc1
// via L3 (proven R8 protocol). Both paths bit-identical results.
template<bool HIST>
__global__ __launch_bounds__(512, 1)
void k_esn(const float* __restrict__ inputs, const short* __restrict__ Wext,
           short* __restrict__ S0, short* __restrict__ S1,
           short* __restrict__ hist, unsigned* __restrict__ cnt,
           float* __restrict__ out)
{
  extern __shared__ __align__(16) char lds[];   // [hb*65536 + col*2048], swizzled
  __shared__ unsigned s_fast;
  const int tid  = threadIdx.x;
  const int g    = blockIdx.x & (NGRP - 1);
  const int rwg  = blockIdx.x >> 5;
  const int wv   = tid >> 6;
  const int lane = tid & 63;
  const int l15  = lane & 15, l4 = lane >> 4;
  const int hi   = wv & 1;
  const int rbase = rwg * 128 + (wv >> 1) * 32;
  const int colbase = g * WGC;
  unsigned* gflags = cnt + g * 16;

  // ---- one-time XCD co-residency verification (L3-scope, proven in R9) ----
  if (tid == 0){
    unsigned x = __builtin_amdgcn_s_getreg(63508);   // hwreg(HW_REG_XCC_ID=20,0,32)
    unsigned v = (x & 0xfu) + 1u;
    unsigned* xs = cnt + 512 + g * 16 + rwg;
    asm volatile("global_store_dword %0, %1, off sc0 sc1" :: "v"(xs), "v"(v) : "memory");
    asm volatile("s_waitcnt vmcnt(0)" ::: "memory");
  }
  __syncthreads();
  if (wv == 0){
    const unsigned* xs = cnt + 512 + g * 16 + (lane & 7);
    unsigned v = 0; int guard = 0;
    for (;;){
      asm volatile("global_load_dword %0, %1, off sc0 sc1\n\t"
                   "s_waitcnt vmcnt(0)" : "=v"(v) : "v"(xs) : "memory");
      if (!__any((int)(v == 0u))) break;
      __builtin_amdgcn_s_sleep(1);
      if (++guard > 1000000) break;
    }
    unsigned v0 = __shfl(v, 0);
    int same = __all((lane < 8) ? (int)(v == v0) : 1);
    if (lane == 0) s_fast = (unsigned)same;
  }
  __syncthreads();
  const bool fast = (s_fast != 0u);

  auto browf = [&](int col, int k) -> const short* {
    if (HIST){
      size_t row = (k <= WARM) ? ((size_t)col * LCH + ((k + 1) & 1))
                               : ((size_t)col * LCH + (size_t)(k - WARM) - 1);
      return hist + row * KE;
    }
    return ((k & 1) ? S1 : S0) + (size_t)col * KE;
  };
  auto wrowf = [&](int col, int k) -> short* {
    if (HIST){
      size_t row = (k < WARM) ? ((size_t)col * LCH + (k & 1))
                              : ((size_t)col * LCH + (size_t)(k - WARM));
      return hist + row * KE;
    }
    return ((k & 1) ? S0 : S1) + (size_t)col * KE;
  };

  // ---- loop-invariant A fragments ----
  const int NA = hi ? 16 : 17;
  const int KB = hi ? 17 : 0;
  const int NL = hi ? 15 : 17;
  short8 a0[17], a1[17];
  {
    const short* abase = Wext + (size_t)(rbase + l15) * KE + l4 * 8;
    #pragma unroll
    for (int i = 0; i < 17; ++i){
      if (i < NA){
        const short* ap = abase + (KB + i) * 32;
        a0[i] = *(const short8*)ap;
        a1[i] = *(const short8*)(ap + (size_t)16 * KE);
      }
    }
  }

  const int scol = tid >> 4;
  const int skb0 = (tid & 15) << 4;
  const int sswz = (scol & 7) << 4;
  const int colb0 = l15 * 2048;
  const int bswz  = (l15 & 7) << 4;
  const int l4b   = l4 * 16;
  const int xsw = (lane * 16) ^ ((lane >> 3) << 4);

  for (int k = 0; k < STEPS; ++k){
    #pragma unroll
    for (int hb = 0; hb < 2; ++hb){
      // ---- wait for producers of this half's inputs ----
      if (k > 0){
        if (wv == 0){
          const unsigned* fp = gflags + (lane & 7);
          unsigned target = (unsigned)(2 * k - 1 + hb);
          int guard = 0;
          for (;;){
            unsigned pv;
            if (fast) POLL1("sc0"); else POLL1("sc0 sc1");
            if (!__any((int)(pv < target))) break;
            __builtin_amdgcn_s_sleep(1);
            if (++guard > 1000000) break;
          }
        }
        __syncthreads();                      // A
      }

      // ---- K-ext tail B loads (issue early) ----
      unsigned long long t00 = 0, t01 = 0, t10 = 0, t11 = 0;
      if (hi){
        const char* tp0 = (const char*)(browf(colbase + hb * 32 + l15, k) + 1024 + l4 * 8);
        const char* tp1 = (const char*)(browf(colbase + hb * 32 + 16 + l15, k) + 1024 + l4 * 8);
        if (fast) TAIL4("sc0"); else TAIL4("sc0 sc1");
      }

      // ---- stage this half's B (32 cols, 64KB) into LDS ----
      {
        const char* sp = (const char*)browf(colbase + hb * 32 + scol, k) + skb0;
        u32x4 r0,r1,r2,r3,r4,r5,r6,r7;
        if (fast) STAGE8("sc0"); else STAGE8("sc0 sc1");
        char* dst = &lds[hb * 65536 + scol * 2048];
        *(u32x4*)(dst + ((skb0 +    0) ^ sswz)) = r0;
        *(u32x4*)(dst + ((skb0 +  256) ^ sswz)) = r1;
        *(u32x4*)(dst + ((skb0 +  512) ^ sswz)) = r2;
        *(u32x4*)(dst + ((skb0 +  768) ^ sswz)) = r3;
        *(u32x4*)(dst + ((skb0 + 1024) ^ sswz)) = r4;
        *(u32x4*)(dst + ((skb0 + 1280) ^ sswz)) = r5;
        *(u32x4*)(dst + ((skb0 + 1536) ^ sswz)) = r6;
        *(u32x4*)(dst + ((skb0 + 1792) ^ sswz)) = r7;
      }
      __syncthreads();                        // B (+ prev-half stores drained per-wave)

      // signal "H0 outputs of step k ready"
      if (hb == 1 && tid == 0 && (k + 1) < STEPS){
        unsigned* fw = gflags + rwg;
        unsigned fv = (unsigned)(2 * k + 1);
        if (fast) asm volatile("global_store_dword %0, %1, off sc0" :: "v"(fw), "v"(fv) : "memory");
        else      asm volatile("global_store_dword %0, %1, off sc0 sc1" :: "v"(fw), "v"(fv) : "memory");
      }

      // ---- MFMA K-loop ----
      f32x4 acc00 = {0,0,0,0}, acc01 = {0,0,0,0}, acc10 = {0,0,0,0}, acc11 = {0,0,0,0};
      const char* bbase = &lds[hb * 65536 + colb0];
      #pragma unroll
      for (int i = 0; i < 17; ++i){
        if (i < NL){
          int kb = (KB + i) * 64 + l4b;
          const short8 b0 = *(const short8*)(bbase + ((kb) ^ bswz));
          const short8 b1 = *(const short8*)(bbase + 32768 + ((kb) ^ bswz));
          acc00 = __builtin_amdgcn_mfma_f32_16x16x32_bf16(a0[i], b0, acc00, 0, 0, 0);
          acc01 = __builtin_amdgcn_mfma_f32_16x16x32_bf16(a0[i], b1, acc01, 0, 0, 0);
          acc10 = __builtin_amdgcn_mfma_f32_16x16x32_bf16(a1[i], b0, acc10, 0, 0, 0);
          acc11 = __builtin_amdgcn_mfma_f32_16x16x32_bf16(a1[i], b1, acc11, 0, 0, 0);
        }
      }
      if (hi){
        u32x4 v0; v0.x=(unsigned)t00; v0.y=(unsigned)(t00>>32); v0.z=(unsigned)t01; v0.w=(unsigned)(t01>>32);
        u32x4 v1; v1.x=(unsigned)t10; v1.y=(unsigned)(t10>>32); v1.z=(unsigned)t11; v1.w=(unsigned)(t11>>32);
        const short8 b0 = __builtin_bit_cast(short8, v0);
        const short8 b1 = __builtin_bit_cast(short8, v1);
        acc00 = __builtin_amdgcn_mfma_f32_16x16x32_bf16(a0[15], b0, acc00, 0, 0, 0);
        acc01 = __builtin_amdgcn_mfma_f32_16x16x32_bf16(a0[15], b1, acc01, 0, 0, 0);
        acc10 = __builtin_amdgcn_mfma_f32_16x16x32_bf16(a1[15], b0, acc10, 0, 0, 0);
        acc11 = __builtin_amdgcn_mfma_f32_16x16x32_bf16(a1[15], b1, acc11, 0, 0, 0);
      }

      // ---- cross-pair K-reduction ----
      __syncthreads();                        // C
      {
        char* eb = &lds[hb * 65536];
        *(f32x4*)(eb + wv * 1024 + xsw)        = hi ? acc00 : acc10;
        *(f32x4*)(eb + 8192 + wv * 1024 + xsw) = hi ? acc01 : acc11;
      }
      __syncthreads();                        // D
      {
        const char* eb = &lds[hb * 65536];
        f32x4 p0 = *(const f32x4*)(eb + (wv ^ 1) * 1024 + xsw);
        f32x4 p1 = *(const f32x4*)(eb + 8192 + (wv ^ 1) * 1024 + xsw);
        f32x4 f0 = (hi ? acc10 : acc00) + p0;
        f32x4 f1 = (hi ? acc11 : acc01) + p1;
        const int rowb = rbase + hi * 16 + l4 * 4;
        #pragma unroll
        for (int ct = 0; ct < 2; ++ct){
          f32x4 z = ct ? f1 : f0;
          float s0 = fast_tanh(z[0]), s1 = fast_tanh(z[1]);
          float s2 = fast_tanh(z[2]), s3 = fast_tanh(z[3]);
          unsigned long long pk = (unsigned long long)f2bf(s0)
            | ((unsigned long long)f2bf(s1) << 16)
            | ((unsigned long long)f2bf(s2) << 32)
            | ((unsigned long long)f2bf(s3) << 48);
          int col = colbase + hb * 32 + ct * 16 + l15;
          short* wp = wrowf(col, k) + rowb;
          if (fast) asm volatile("global_store_dwordx2 %0, %1, off sc0" :: "v"(wp), "v"(pk) : "memory");
          else      asm volatile("global_store_dwordx2 %0, %1, off sc0 sc1" :: "v"(wp), "v"(pk) : "memory");
          if (!HIST && k >= WARM){
            int tk = col * LCH + k - WARM;
            float* op = out + (size_t)rowb * T_LEN + tk;
            op[0] = s0; op[(size_t)T_LEN] = s1;
            op[(size_t)2 * T_LEN] = s2; op[(size_t)3 * T_LEN] = s3;
          }
        }
      }

      // ---- x for next step (this half's cols; rwg0 only) ----
      if (rwg == 0 && (tid >> 5) == hb && tid < 64 && (k + 1) < STEPS){
        int col = colbase + tid;
        short* xr = wrowf(col, k) + 1024;
        int tn = col * LCH + (k + 1) - WARM;
        u32x4 xv = {0,0,0,0};
        if (tn >= 0){
          const float4 A4 = *(const float4*)(inputs + (size_t)tn * 8);
          const float4 B4 = *(const float4*)(inputs + (size_t)tn * 8 + 4);
          xv.x = f2bf(A4.x) | ((unsigned)f2bf(A4.y) << 16);
          xv.y = f2bf(A4.z) | ((unsigned)f2bf(A4.w) << 16);
          xv.z = f2bf(B4.x) | ((unsigned)f2bf(B4.y) << 16);
          xv.w = f2bf(B4.z) | ((unsigned)f2bf(B4.w) << 16);
        }
        if (fast) asm volatile("global_store_dwordx4 %0, %1, off sc0" :: "v"(xr), "v"(xv) : "memory");
        else      asm volatile("global_store_dwordx4 %0, %1, off sc0 sc1" :: "v"(xr), "v"(xv) : "memory");
      }
      // H0: stores left in flight (drained by H1's staging vmcnt(0)).
    }

    // ---- end of step: drain H1 stores, signal 2k+2 ----
    asm volatile("s_waitcnt vmcnt(0)" ::: "memory");
    __syncthreads();                          // E
    if (tid == 0 && (k + 1) < STEPS){
      unsigned* fw = gflags + rwg;
      unsigned fv = (unsigned)(2 * k + 2);
      if (fast) asm volatile("global_store_dword %0, %1, off sc0" :: "v"(fw), "v"(fv) : "memory");
      else      asm volatile("global_store_dword %0, %1, off sc0 sc1" :: "v"(fw), "v"(fv) : "memory");
    }
  }
}

extern "C" void kernel_launch(void* const* d_in, const int* in_sizes, int n_in,
                              void* d_out, int out_size, void* d_ws, size_t ws_size,
                              hipStream_t stream)
{
  (void)in_sizes; (void)n_in; (void)out_size;
  const float* inputs = (const float*)d_in[0];
  const float* Win    = (const float*)d_in[1];
  const float* Wres   = (const float*)d_in[2];
  float* out = (float*)d_out;
  char* ws = (char*)d_ws;

  short*    Wext = (short*)(ws);                       // 2,162,688 B
  unsigned* cnt  = (unsigned*)(ws + 2162688);          // 4096 B: flags + xcc slots
  char*     data = ws + 2166784;
  short*    hist = (short*)data;                       // 65536*1056*2 = 138,412,032 B
  short*    S0   = (short*)data;                       // !HIST: 2048*1056*2 B
  short*    S1   = (short*)(data + 4325376);
  const bool hist_ok = ws_size >= (2166784ull + 138412032ull);

  hipLaunchKernelGGL(k_build_wext, dim3(4224), dim3(256), 0, stream, Wres, Win, Wext);
  hipLaunchKernelGGL(k_xrows,      dim3(256),  dim3(256), 0, stream, inputs, out);
  if (hist_ok){
    hipLaunchKernelGGL(k_zero_init, dim3(4096), dim3(256), 0, stream,
                       hist + KE, (size_t)LCH * KE);
    hipLaunchKernelGGL(k_init_x,    dim3(8),    dim3(256), 0, stream,
                       inputs, hist + KE + 1024, (size_t)LCH * KE, cnt);
    hipLaunchKernelGGL((k_esn<true>),  dim3(RWG * NGRP), dim3(512), LDSB, stream,
                       inputs, Wext, S0, S1, hist, cnt, out);
    hipLaunchKernelGGL(k_transpose, dim3(1024, 16), dim3(256), 0, stream, hist, out);
  } else {
    hipLaunchKernelGGL(k_zero_init, dim3(4096), dim3(256), 0, stream,
                       S0, (size_t)KE);
    hipLaunchKernelGGL(k_init_x,    dim3(8),    dim3(256), 0, stream,
                       inputs, S0 + 1024, (size_t)KE, cnt);
    hipLaunchKernelGGL((k_esn<false>), dim3(RWG * NGRP), dim3(512), LDSB, stream,
                       inputs, Wext, S0, S1, hist, cnt, out);
  }
}

// Round 11
// 524.231 us; speedup vs baseline: 3903.1303x; 3903.1303x over previous
//
#include <hip/hip_runtime.h>
#include <cstdint>

typedef __attribute__((ext_vector_type(8))) short short8;
typedef __attribute__((ext_vector_type(4))) float f32x4;
typedef __attribute__((ext_vector_type(4))) unsigned u32x4;

#define R_DIM 1024
#define KE    1056      // 1024 state + 8 x + 24 zero pad
#define T_LEN 65536
#define CCH   2048      // chunks
#define LCH   32        // real steps per chunk
#define WARM  12        // warmup steps (validated R9/R10: absmax 0.0307)
#define STEPS (WARM + LCH)   // 44
#define NGRP  64        // groups, 32 cols each; each WG serves 2 groups
#define RWG   8         // row-WGs per group (128 rows each)
#define LDSB  131072    // 2 group-regions x 32 cols x 2048B

static __device__ __forceinline__ unsigned short f2bf(float f){
  unsigned u = __builtin_bit_cast(unsigned, f);
  u += 0x7fffu + ((u >> 16) & 1u);
  return (unsigned short)(u >> 16);
}
static __device__ __forceinline__ float fast_tanh(float x){
  float e = __expf(2.0f * x);          // inf/0 saturate correctly to +/-1
  return 1.0f - 2.0f / (e + 1.0f);
}

// ---- prep: W_ext = [W_res | W_in | 0] in bf16, row-major [1024][1056] ----
__global__ void k_build_wext(const float* __restrict__ Wres,
                             const float* __restrict__ Win,
                             short* __restrict__ Wext){
  int idx = blockIdx.x * 256 + threadIdx.x;       // 1024*1056 = 4224*256
  int r = idx / KE, k = idx % KE;
  float v = 0.0f;
  if (k < 1024)      v = Wres[(size_t)r * 1024 + k];
  else if (k < 1032) v = Win[r * 8 + (k - 1024)];
  Wext[idx] = (short)f2bf(v);
}

// ---- prep: zero state region [0,1024) of each chunk's initial-read row ----
__global__ void k_zero_init(short* __restrict__ base, size_t rowstride){
  int idx = blockIdx.x * 256 + threadIdx.x;   // 2048 rows x 512 dwords
  int c = idx >> 9, d = idx & 511;
  ((unsigned*)(base + (size_t)c * rowstride))[d] = 0u;
}

// ---- prep: x-slot of each chunk's initial row, zero flags ----
__global__ void k_init_x(const float* __restrict__ in, short* __restrict__ x0,
                         size_t rowstride, unsigned* __restrict__ cnt){
  int c = blockIdx.x * 256 + threadIdx.x;
  if (c < 1024) cnt[c] = 0u;                  // 64 groups x 16 dwords
  if (c < CCH){
    int t0 = c * LCH - WARM;
    uint4 xv = {0,0,0,0};
    if (t0 >= 0){
      const float4 A4 = *(const float4*)(in + (size_t)t0 * 8);
      const float4 B4 = *(const float4*)(in + (size_t)t0 * 8 + 4);
      xv.x = f2bf(A4.x) | ((unsigned)f2bf(A4.y) << 16);
      xv.y = f2bf(A4.z) | ((unsigned)f2bf(A4.w) << 16);
      xv.z = f2bf(B4.x) | ((unsigned)f2bf(B4.y) << 16);
      xv.w = f2bf(B4.z) | ((unsigned)f2bf(B4.w) << 16);
    }
    *(uint4*)(x0 + (size_t)c * rowstride) = xv;
  }
}

// ---- output rows 1024..1031 = inputs^T (exact fp32 copy) ----
__global__ void k_xrows(const float* __restrict__ in, float* __restrict__ out){
  int t = blockIdx.x * 256 + threadIdx.x;
  const float4 a = *(const float4*)(in + (size_t)t * 8);
  const float4 b = *(const float4*)(in + (size_t)t * 8 + 4);
  out[(size_t)(R_DIM + 0) * T_LEN + t] = a.x;
  out[(size_t)(R_DIM + 1) * T_LEN + t] = a.y;
  out[(size_t)(R_DIM + 2) * T_LEN + t] = a.z;
  out[(size_t)(R_DIM + 3) * T_LEN + t] = a.w;
  out[(size_t)(R_DIM + 4) * T_LEN + t] = b.x;
  out[(size_t)(R_DIM + 5) * T_LEN + t] = b.y;
  out[(size_t)(R_DIM + 6) * T_LEN + t] = b.z;
  out[(size_t)(R_DIM + 7) * T_LEN + t] = b.w;
}

// ---- hist[t][r] (bf16) -> out[r][t] (f32), tiled transpose ----
__global__ void k_transpose(const short* __restrict__ hist, float* __restrict__ out){
  __shared__ float tile[64][65];
  const int t0 = blockIdx.x * 64;
  const int r0 = blockIdx.y * 64;
  for (int it = 0; it < 2; ++it){
    int id = it * 256 + threadIdx.x;     // 512 chunks of 8 bf16
    int tr = id >> 3;
    int c8 = (id & 7) * 8;
    short8 v = *(const short8*)(hist + (size_t)(t0 + tr) * KE + r0 + c8);
    #pragma unroll
    for (int j = 0; j < 8; ++j){
      unsigned u = ((unsigned)(unsigned short)v[j]) << 16;
      tile[tr][c8 + j] = __builtin_bit_cast(float, u);
    }
  }
  __syncthreads();
  #pragma unroll
  for (int p = 0; p < 16; ++p){
    int rr = (threadIdx.x >> 6) + p * 4;
    int tc = threadIdx.x & 63;
    out[(size_t)(r0 + rr) * T_LEN + t0 + tc] = tile[tc][rr];
  }
}

// issue 8 staging loads, NO wait (prefix p, pointer sp in scope)
#define STAGE8I(p, sfx) \
  asm volatile( \
    "global_load_dwordx4 %0, %8, off " sfx "\n\t" \
    "global_load_dwordx4 %1, %8, off offset:256 " sfx "\n\t" \
    "global_load_dwordx4 %2, %8, off offset:512 " sfx "\n\t" \
    "global_load_dwordx4 %3, %8, off offset:768 " sfx "\n\t" \
    "global_load_dwordx4 %4, %8, off offset:1024 " sfx "\n\t" \
    "global_load_dwordx4 %5, %8, off offset:1280 " sfx "\n\t" \
    "global_load_dwordx4 %6, %8, off offset:1536 " sfx "\n\t" \
    "global_load_dwordx4 %7, %8, off offset:1792 " sfx \
    : "=&v"(p##0),"=&v"(p##1),"=&v"(p##2),"=&v"(p##3), \
      "=&v"(p##4),"=&v"(p##5),"=&v"(p##6),"=&v"(p##7) \
    : "v"(sp) : "memory")

// issue 4 tail dwordx2 loads, NO wait (pointers tp0/tp1 in scope)
#define TAIL4I(t0_,t1_,t2_,t3_) \
  asm volatile( \
    "global_load_dwordx2 %0, %4, off sc0 sc1\n\t" \
    "global_load_dwordx2 %1, %4, off offset:8 sc0 sc1\n\t" \
    "global_load_dwordx2 %2, %5, off sc0 sc1\n\t" \
    "global_load_dwordx2 %3, %5, off offset:8 sc0 sc1" \
    : "=&v"(t0_),"=&v"(t1_),"=&v"(t2_),"=&v"(t3_) \
    : "v"(tp0), "v"(tp1) : "memory")

#define LDSW8(p, dst) do { \
  *(u32x4*)(dst + ((skb0 +    0) ^ sswz)) = p##0; \
  *(u32x4*)(dst + ((skb0 +  256) ^ sswz)) = p##1; \
  *(u32x4*)(dst + ((skb0 +  512) ^ sswz)) = p##2; \
  *(u32x4*)(dst + ((skb0 +  768) ^ sswz)) = p##3; \
  *(u32x4*)(dst + ((skb0 + 1024) ^ sswz)) = p##4; \
  *(u32x4*)(dst + ((skb0 + 1280) ^ sswz)) = p##5; \
  *(u32x4*)(dst + ((skb0 + 1536) ^ sswz)) = p##6; \
  *(u32x4*)(dst + ((skb0 + 1792) ^ sswz)) = p##7; } while(0)

// ---- main: 256 WGs x 512 thr (1 WG/CU). Each WG = 128 rows x TWO independent
// 32-col groups (gA = bid&31, gB = gA+32; same A rows -> A-frags shared).
// Phase-interleave: stage-A flight covers poll-B; stage-B flight covers
// MFMA-A; gA signaled mid-iteration. ALL cross-WG protocol ops are sc0 sc1
// (coherence point) — R9/R10 proved L2-local sync nonviable. Bulk staging of
// write-once rows (k>WARM+2) uses plain cached loads (R7-proven: write-once,
// flag-gated, value-deterministic across replays); group's 8 WGs sit on one
// XCD (bid&31=g => bid%8=g%8) so redundant reads hit shared L2.
template<bool HIST>
__global__ __launch_bounds__(512, 1)
void k_esn(const float* __restrict__ inputs, const short* __restrict__ Wext,
           short* __restrict__ S0, short* __restrict__ S1,
           short* __restrict__ hist, unsigned* __restrict__ cnt,
           float* __restrict__ out)
{
  extern __shared__ __align__(16) char lds[];   // [grp*65536 + col*2048], swizzled
  const int tid  = threadIdx.x;
  const int gA   = blockIdx.x & 31;
  const int gB   = gA + 32;
  const int rwg  = blockIdx.x >> 5;
  const int wv   = tid >> 6;
  const int lane = tid & 63;
  const int l15  = lane & 15, l4 = lane >> 4;
  const int hi   = wv & 1;
  const int rbase = rwg * 128 + (wv >> 1) * 32;
  const int colA = gA * 32, colB = gB * 32;
  unsigned* fA = cnt + gA * 16;
  unsigned* fB = cnt + gB * 16;

  auto browf = [&](int col, int k) -> const short* {
    if (HIST){
      size_t row = (k <= WARM) ? ((size_t)col * LCH + ((k + 1) & 1))
                               : ((size_t)col * LCH + (size_t)(k - WARM) - 1);
      return hist + row * KE;
    }
    return ((k & 1) ? S1 : S0) + (size_t)col * KE;
  };
  auto wrowf = [&](int col, int k) -> short* {
    if (HIST){
      size_t row = (k < WARM) ? ((size_t)col * LCH + (k & 1))
                              : ((size_t)col * LCH + (size_t)(k - WARM));
      return hist + row * KE;
    }
    return ((k & 1) ? S0 : S1) + (size_t)col * KE;
  };

  // ---- loop-invariant A fragments (shared by both groups: same rows) ----
  const int NA = hi ? 16 : 17;
  const int KB = hi ? 17 : 0;
  const int NL = hi ? 15 : 17;
  short8 a0[17], a1[17];
  {
    const short* abase = Wext + (size_t)(rbase + l15) * KE + l4 * 8;
    #pragma unroll
    for (int i = 0; i < 17; ++i){
      if (i < NA){
        const short* ap = abase + (KB + i) * 32;
        a0[i] = *(const short8*)ap;
        a1[i] = *(const short8*)(ap + (size_t)16 * KE);
      }
    }
  }

  const int scol = tid >> 4;
  const int skb0 = (tid & 15) << 4;
  const int sswz = (scol & 7) << 4;
  const int colb0 = l15 * 2048;
  const int bswz  = (l15 & 7) << 4;
  const int l4b   = l4 * 16;
  const int xsw = (lane * 16) ^ ((lane >> 3) << 4);

  auto pollwait = [&](unsigned* flags, unsigned target){
    if (wv == 0){
      const unsigned* fp = flags + (lane & 7);
      int guard = 0;
      for (;;){
        unsigned pv;
        asm volatile("global_load_dword %0, %1, off sc0 sc1\n\t"
                     "s_waitcnt vmcnt(0)" : "=v"(pv) : "v"(fp) : "memory");
        if (!__any((int)(pv < target))) break;
        __builtin_amdgcn_s_sleep(1);
        if (++guard > 1000000) break;        // failsafe: degrade, don't hang
      }
    }
    __syncthreads();
  };

  auto mfma_phase = [&](const char* bbase,
                        unsigned long long t00, unsigned long long t01,
                        unsigned long long t10, unsigned long long t11,
                        f32x4& A00, f32x4& A01, f32x4& A10, f32x4& A11){
    A00 = f32x4{0,0,0,0}; A01 = f32x4{0,0,0,0};
    A10 = f32x4{0,0,0,0}; A11 = f32x4{0,0,0,0};
    #pragma unroll
    for (int i = 0; i < 17; ++i){
      if (i < NL){
        int kb = (KB + i) * 64 + l4b;
        const short8 b0 = *(const short8*)(bbase + ((kb) ^ bswz));
        const short8 b1 = *(const short8*)(bbase + 32768 + ((kb) ^ bswz));
        A00 = __builtin_amdgcn_mfma_f32_16x16x32_bf16(a0[i], b0, A00, 0, 0, 0);
        A01 = __builtin_amdgcn_mfma_f32_16x16x32_bf16(a0[i], b1, A01, 0, 0, 0);
        A10 = __builtin_amdgcn_mfma_f32_16x16x32_bf16(a1[i], b0, A10, 0, 0, 0);
        A11 = __builtin_amdgcn_mfma_f32_16x16x32_bf16(a1[i], b1, A11, 0, 0, 0);
      }
    }
    if (hi){
      u32x4 v0; v0.x=(unsigned)t00; v0.y=(unsigned)(t00>>32); v0.z=(unsigned)t01; v0.w=(unsigned)(t01>>32);
      u32x4 v1; v1.x=(unsigned)t10; v1.y=(unsigned)(t10>>32); v1.z=(unsigned)t11; v1.w=(unsigned)(t11>>32);
      const short8 b0 = __builtin_bit_cast(short8, v0);
      const short8 b1 = __builtin_bit_cast(short8, v1);
      A00 = __builtin_amdgcn_mfma_f32_16x16x32_bf16(a0[15], b0, A00, 0, 0, 0);
      A01 = __builtin_amdgcn_mfma_f32_16x16x32_bf16(a0[15], b1, A01, 0, 0, 0);
      A10 = __builtin_amdgcn_mfma_f32_16x16x32_bf16(a1[15], b0, A10, 0, 0, 0);
      A11 = __builtin_amdgcn_mfma_f32_16x16x32_bf16(a1[15], b1, A11, 0, 0, 0);
    }
  };

  // exchange + tanh + stores (+x for next step); stores left IN FLIGHT
  auto finish = [&](f32x4 A00, f32x4 A01, f32x4 A10, f32x4 A11,
                    char* eb, int cb, int k){
    __syncthreads();                        // C: all done reading this LDS region
    *(f32x4*)(eb + wv * 1024 + xsw)        = hi ? A00 : A10;
    *(f32x4*)(eb + 8192 + wv * 1024 + xsw) = hi ? A01 : A11;
    __syncthreads();                        // D
    f32x4 p0 = *(const f32x4*)(eb + (wv ^ 1) * 1024 + xsw);
    f32x4 p1 = *(const f32x4*)(eb + 8192 + (wv ^ 1) * 1024 + xsw);
    f32x4 z0 = (hi ? A10 : A00) + p0;
    f32x4 z1 = (hi ? A11 : A01) + p1;
    const int rowb = rbase + hi * 16 + l4 * 4;
    #pragma unroll
    for (int ct = 0; ct < 2; ++ct){
      f32x4 z = ct ? z1 : z0;
      float s0 = fast_tanh(z[0]), s1 = fast_tanh(z[1]);
      float s2 = fast_tanh(z[2]), s3 = fast_tanh(z[3]);
      unsigned long long pk = (unsigned long long)f2bf(s0)
        | ((unsigned long long)f2bf(s1) << 16)
        | ((unsigned long long)f2bf(s2) << 32)
        | ((unsigned long long)f2bf(s3) << 48);
      int col = cb + ct * 16 + l15;
      short* wp = wrowf(col, k) + rowb;
      asm volatile("global_store_dwordx2 %0, %1, off sc0 sc1"
                   :: "v"(wp), "v"(pk) : "memory");
      if (!HIST && k >= WARM){
        int tk = col * LCH + k - WARM;
        float* op = out + (size_t)rowb * T_LEN + tk;
        op[0] = s0; op[(size_t)T_LEN] = s1;
        op[(size_t)2 * T_LEN] = s2; op[(size_t)3 * T_LEN] = s3;
      }
    }
    if (rwg == 0 && tid < 32 && (k + 1) < STEPS){
      int col = cb + tid;
      short* xr = wrowf(col, k) + 1024;
      int tn = col * LCH + (k + 1) - WARM;
      u32x4 xv = {0,0,0,0};
      if (tn >= 0){
        const float4 A4 = *(const float4*)(inputs + (size_t)tn * 8);
        const float4 B4 = *(const float4*)(inputs + (size_t)tn * 8 + 4);
        xv.x = f2bf(A4.x) | ((unsigned)f2bf(A4.y) << 16);
        xv.y = f2bf(A4.z) | ((unsigned)f2bf(A4.w) << 16);
        xv.z = f2bf(B4.x) | ((unsigned)f2bf(B4.y) << 16);
        xv.w = f2bf(B4.z) | ((unsigned)f2bf(B4.w) << 16);
      }
      asm volatile("global_store_dwordx4 %0, %1, off sc0 sc1"
                   :: "v"(xr), "v"(xv) : "memory");
    }
  };

  for (int k = 0; k < STEPS; ++k){
    const bool coh = (!HIST) || (k <= WARM + 2);

    // ---- phase A: poll, issue loads ----
    if (k > 0) pollwait(fA, (unsigned)k);
    unsigned long long tA0=0, tA1=0, tA2=0, tA3=0;
    if (hi){
      const char* tp0 = (const char*)(browf(colA + l15, k) + 1024 + l4 * 8);
      const char* tp1 = (const char*)(browf(colA + 16 + l15, k) + 1024 + l4 * 8);
      TAIL4I(tA0, tA1, tA2, tA3);
    }
    u32x4 ar0,ar1,ar2,ar3,ar4,ar5,ar6,ar7;
    {
      const char* sp = (const char*)browf(colA + scol, k) + skb0;
      if (coh) STAGE8I(ar, "sc0 sc1"); else STAGE8I(ar, "");
    }

    // ---- poll B while A's loads are in flight ----
    if (k > 0) pollwait(fB, (unsigned)k);

    // ---- A loads done -> LDS region A ----
    asm volatile("s_waitcnt vmcnt(0)" ::: "memory");
    LDSW8(ar, (&lds[scol * 2048]));
    __syncthreads();                        // LDS A ready

    // ---- issue B's tail + staging (flight covers MFMA A) ----
    unsigned long long tB0=0, tB1=0, tB2=0, tB3=0;
    if (hi){
      const char* tp0 = (const char*)(browf(colB + l15, k) + 1024 + l4 * 8);
      const char* tp1 = (const char*)(browf(colB + 16 + l15, k) + 1024 + l4 * 8);
      TAIL4I(tB0, tB1, tB2, tB3);
    }
    u32x4 br0,br1,br2,br3,br4,br5,br6,br7;
    {
      const char* sp = (const char*)browf(colB + scol, k) + skb0;
      if (coh) STAGE8I(br, "sc0 sc1"); else STAGE8I(br, "");
    }

    // ---- MFMA A + finish A (stores in flight) ----
    f32x4 A00, A01, A10, A11;
    mfma_phase(&lds[colb0], tA0, tA1, tA2, tA3, A00, A01, A10, A11);
    finish(A00, A01, A10, A11, &lds[0], colA, k);

    // ---- drain (B loads + A stores), signal A mid-iteration ----
    asm volatile("s_waitcnt vmcnt(0)" ::: "memory");
    __syncthreads();
    if (tid == 0 && (k + 1) < STEPS){
      unsigned* fw = fA + rwg;
      unsigned fv = (unsigned)(k + 1);
      asm volatile("global_store_dword %0, %1, off sc0 sc1"
                   :: "v"(fw), "v"(fv) : "memory");
    }

    // ---- LDS region B, MFMA B, finish B ----
    LDSW8(br, (&lds[65536 + scol * 2048]));
    __syncthreads();                        // LDS B ready
    f32x4 B00, B01, B10, B11;
    mfma_phase(&lds[65536 + colb0], tB0, tB1, tB2, tB3, B00, B01, B10, B11);
    finish(B00, B01, B10, B11, &lds[65536], colB, k);

    // ---- drain B stores, signal B ----
    asm volatile("s_waitcnt vmcnt(0)" ::: "memory");
    __syncthreads();
    if (tid == 0 && (k + 1) < STEPS){
      unsigned* fw = fB + rwg;
      unsigned fv = (unsigned)(k + 1);
      asm volatile("global_store_dword %0, %1, off sc0 sc1"
                   :: "v"(fw), "v"(fv) : "memory");
    }
  }
}

extern "C" void kernel_launch(void* const* d_in, const int* in_sizes, int n_in,
                              void* d_out, int out_size, void* d_ws, size_t ws_size,
                              hipStream_t stream)
{
  (void)in_sizes; (void)n_in; (void)out_size;
  const float* inputs = (const float*)d_in[0];
  const float* Win    = (const float*)d_in[1];
  const float* Wres   = (const float*)d_in[2];
  float* out = (float*)d_out;
  char* ws = (char*)d_ws;

  short*    Wext = (short*)(ws);                       // 2,162,688 B
  unsigned* cnt  = (unsigned*)(ws + 2162688);          // 4096 B: 64 groups x 16 dw
  char*     data = ws + 2166784;
  short*    hist = (short*)data;                       // 65536*1056*2 = 138,412,032 B
  short*    S0   = (short*)data;                       // !HIST: 2048*1056*2 B
  short*    S1   = (short*)(data + 4325376);
  const bool hist_ok = ws_size >= (2166784ull + 138412032ull);

  hipLaunchKernelGGL(k_build_wext, dim3(4224), dim3(256), 0, stream, Wres, Win, Wext);
  hipLaunchKernelGGL(k_xrows,      dim3(256),  dim3(256), 0, stream, inputs, out);
  if (hist_ok){
    hipLaunchKernelGGL(k_zero_init, dim3(4096), dim3(256), 0, stream,
                       hist + KE, (size_t)LCH * KE);
    hipLaunchKernelGGL(k_init_x,    dim3(8),    dim3(256), 0, stream,
                       inputs, hist + KE + 1024, (size_t)LCH * KE, cnt);
    hipLaunchKernelGGL((k_esn<true>),  dim3(256), dim3(512), LDSB, stream,
                       inputs, Wext, S0, S1, hist, cnt, out);
    hipLaunchKernelGGL(k_transpose, dim3(1024, 16), dim3(256), 0, stream, hist, out);
  } else {
    hipLaunchKernelGGL(k_zero_init, dim3(4096), dim3(256), 0, stream,
                       S0, (size_t)KE);
    hipLaunchKernelGGL(k_init_x,    dim3(8),    dim3(256), 0, stream,
                       inputs, S0 + 1024, (size_t)KE, cnt);
    hipLaunchKernelGGL((k_esn<false>), dim3(256), dim3(512), LDSB, stream,
                       inputs, Wext, S0, S1, hist, cnt, out);
  }
}